// Round 8
// baseline (233.944 us; speedup 1.0000x reference)
//
#include <hip/hip_runtime.h>
#include <hip/hip_bf16.h>
#include <cstdint>

#define B_SZ 4
#define T_SZ 2048
#define C_SZ 1024
#define H_SZ 16
#define D_SZ 64
#define BT_SZ (B_SZ * T_SZ)     // 8192
#define C3_SZ (3 * C_SZ)        // 3072
#define NKC (C_SZ / 32)         // 32 K-chunks

typedef __attribute__((ext_vector_type(8))) short bf16x8;
typedef __attribute__((ext_vector_type(4))) float f32x4;
typedef __attribute__((ext_vector_type(4))) unsigned short ushort4v;
typedef __attribute__((ext_vector_type(4))) unsigned int uint4v;

typedef __attribute__((address_space(3))) unsigned int lds_u32;
typedef __attribute__((address_space(1))) const unsigned int glb_u32;

__device__ __forceinline__ unsigned short f2bf(float f) {
  unsigned u = __builtin_bit_cast(unsigned, f);
  u += 0x7fffu + ((u >> 16) & 1u);  // round-to-nearest-even
  return (unsigned short)(u >> 16);
}

// pack two fp32 -> two bf16 (truncating) in ONE v_perm_b32
__device__ __forceinline__ unsigned packbf2(float lo, float hi) {
  return __builtin_amdgcn_perm(__builtin_bit_cast(unsigned, hi),
                               __builtin_bit_cast(unsigned, lo), 0x07060302u);
}

// async global->LDS, 16B per lane; LDS dest = wave-uniform base + lane*16
__device__ __forceinline__ void gll16(const unsigned short* g,
                                      unsigned short* l) {
  __builtin_amdgcn_global_load_lds((glb_u32*)g, (lds_u32*)l, 16, 0, 0);
}

// ===========================================================================
// Fragment layouts (verified rounds 2-7):
//  A-frag blocked: elem(r,k) -> ((tb*NKC+kc)*4+quad)*128 + (r&15)*8 + (k&7)
//  B-frag blocked: same with n = c&15
//  Vf key-permuted PV B-operand: elem(t,d) -> ((gb*4+dv)*4+quad)*128
//      + (d&15)*8 + j,  kk=t&31, quad=(kk>>2)&3, j=(kk>>4)*4+(kk&3)
//
// Round-8:  NEVER cap with __launch_bounds__ min-waves (acc spills, 6x).
// Round-9/10: 8-phase counted-vmcnt schedules lose at this shape; the
//   2-barrier 128^2 loop at ~3 blocks/CU wins here.
// Round-13: attn v7 counters: 56.4us, VGPR 168, MfmaUtil 25%, VALU 51%,
//   Occ 10% -> latency-bound, triangular tail.
// Round-14 (v10 paired 64-row, 1024 waves = 1/SIMD): 57us == v7. Clean
//   A/B: contention between 2 waves/SIMD is ~free (m114), a lone wave runs
//   at dep-chain latency. The lever is balance AND 2 waves/SIMD TOGETHER.
// Round-15: v11 submission aborted with core dump but NO HIP fault string;
//   infra was degraded (931s npz push). Full OOB audit clean; v11 composes
//   round-3-verified chunk logic with round-6-verified pairing. Resubmitted
//   unchanged as a flake A/B.
// ===========================================================================

// ---------------------------------------------------------------------------
// pack_all: fused pack_x + pack_w(W_attn) + pack_w(W_proj)
// ---------------------------------------------------------------------------
__device__ __forceinline__ void pack_x_task(const float* __restrict__ x,
                                            unsigned short* __restrict__ Af,
                                            int task, int lane) {
  const int quad = lane >> 4, n = lane & 15;
  const int tb = task >> 5, kc = task & 31;
  const float* src = x + (size_t)(tb * 16 + n) * C_SZ + kc * 32 + quad * 8;
  float4 a = *(const float4*)src;
  float4 b = *(const float4*)(src + 4);
  ushort4v o0, o1;
  o0[0] = f2bf(a.x); o0[1] = f2bf(a.y); o0[2] = f2bf(a.z); o0[3] = f2bf(a.w);
  o1[0] = f2bf(b.x); o1[1] = f2bf(b.y); o1[2] = f2bf(b.z); o1[3] = f2bf(b.w);
  unsigned short* dst = Af + ((size_t)((tb * NKC + kc) * 4 + quad) * 16 + n) * 8;
  *(ushort4v*)dst = o0;
  *(ushort4v*)(dst + 4) = o1;
}

__device__ __forceinline__ void pack_w_task(const float* __restrict__ W,
                                            unsigned short* __restrict__ Wb,
                                            int N, int task, int lane) {
  const int quad = lane >> 4, n = lane & 15;
  const int nt = task >> 5, kc = task & 31;
  const int col = nt * 16 + n;
  const int k0 = kc * 32 + quad * 8;
  ushort4v o0, o1;
#pragma unroll
  for (int i = 0; i < 4; ++i) o0[i] = f2bf(W[(size_t)(k0 + i) * N + col]);
#pragma unroll
  for (int i = 0; i < 4; ++i) o1[i] = f2bf(W[(size_t)(k0 + 4 + i) * N + col]);
  unsigned short* dst = Wb + ((size_t)((nt * NKC + kc) * 4 + quad) * 16 + n) * 8;
  *(ushort4v*)dst = o0;
  *(ushort4v*)(dst + 4) = o1;
}

__global__ __launch_bounds__(256) void pack_all(
    const float* __restrict__ x, const float* __restrict__ Wa,
    const float* __restrict__ Wp, unsigned short* __restrict__ Af,
    unsigned short* __restrict__ Wab, unsigned short* __restrict__ Wpb) {
  const int bx = blockIdx.x;
  const int sub = threadIdx.x >> 6;
  const int lane = threadIdx.x & 63;
  if (bx < 4096) {
    pack_x_task(x, Af, bx * 4 + sub, lane);              // 512 tb x 32 kc
  } else if (bx < 4096 + 1536) {
    pack_w_task(Wa, Wab, C3_SZ, (bx - 4096) * 4 + sub, lane);  // 192 nt x 32
  } else {
    pack_w_task(Wp, Wpb, C_SZ, (bx - 5632) * 4 + sub, lane);   // 64 nt x 32
  }
}

// ---------------------------------------------------------------------------
// m97-style staged GEMM mainloop (verified round 6): 128x128 tile, BK=64,
// global_load_lds(16B) into an LDS image of the fragment-blocked layout.
// ---------------------------------------------------------------------------
__device__ __forceinline__ void gemm128_mainloop(
    const unsigned short* __restrict__ A, const unsigned short* __restrict__ B,
    int tbB, int ntB, unsigned short* smem, f32x4 acc[4][4]) {
  const int tid = threadIdx.x;
  const int w = tid >> 6, lane = tid & 63;
  const int quad = lane >> 4, n = lane & 15;
  const int wr = w >> 1, wc = w & 1;
  unsigned short* smemA = smem;         // 8192 shorts
  unsigned short* smemB = smem + 8192;  // 8192 shorts

  for (int kc0 = 0; kc0 < NKC; kc0 += 2) {
#pragma unroll
    for (int i2 = 0; i2 < 2; ++i2) {
      const int i = 2 * w + i2;
      const unsigned short* gA =
          A + ((size_t)(tbB + i) * NKC + kc0) * 512 + lane * 8;
      const unsigned short* gB =
          B + ((size_t)(ntB + i) * NKC + kc0) * 512 + lane * 8;
      gll16(gA, smemA + i * 1024);
      gll16(gA + 512, smemA + i * 1024 + 512);
      gll16(gB, smemB + i * 1024);
      gll16(gB + 512, smemB + i * 1024 + 512);
    }
    __syncthreads();
#pragma unroll
    for (int kcl = 0; kcl < 2; ++kcl) {
      bf16x8 af[4], bfr[4];
#pragma unroll
      for (int m = 0; m < 4; ++m)
        af[m] = *(const bf16x8*)(smemA + (wr * 4 + m) * 1024 +
                                 (kcl * 4 + quad) * 128 + n * 8);
#pragma unroll
      for (int nn = 0; nn < 4; ++nn)
        bfr[nn] = *(const bf16x8*)(smemB + (wc * 4 + nn) * 1024 +
                                   (kcl * 4 + quad) * 128 + n * 8);
#pragma unroll
      for (int m = 0; m < 4; ++m)
#pragma unroll
        for (int nn = 0; nn < 4; ++nn)
          acc[m][nn] = __builtin_amdgcn_mfma_f32_16x16x32_bf16(
              af[m], bfr[nn], acc[m][nn], 0, 0, 0);
    }
    __syncthreads();
  }
}

// qkv: 1-D grid 1536, XCD-aware swizzle — each XCD (f&7) owns 8 consecutive
// by rows; bx varies fastest.
__global__ __launch_bounds__(256) void qkv_mfma(
    const unsigned short* __restrict__ Af, const unsigned short* __restrict__ Wab,
    const float* __restrict__ bias, unsigned short* __restrict__ Qf,
    unsigned short* __restrict__ Kf, unsigned short* __restrict__ Vf) {
  __shared__ unsigned short smem[16384];
  const int tid = threadIdx.x;
  const int w = tid >> 6, lane = tid & 63;
  const int quad = lane >> 4, n = lane & 15;
  const int wr = w >> 1, wc = w & 1;
  const int f = blockIdx.x;
  const int xcd = f & 7, i = f >> 3;
  const int by = xcd * 8 + (i / 24);   // [0,64)
  const int bx = i % 24;               // [0,24)
  f32x4 acc[4][4];
#pragma unroll
  for (int m = 0; m < 4; ++m)
#pragma unroll
    for (int nn = 0; nn < 4; ++nn) acc[m][nn] = (f32x4){0.f, 0.f, 0.f, 0.f};

  gemm128_mainloop(Af, Wab, by * 8, bx * 8, smem, acc);

  const int cb = bx * 128 + wc * 64;
  const int which = cb >> 10;
  const int h = (cb & 1023) >> 6;
  const int gr0 = by * 128 + wr * 64;
  const int b = gr0 >> 11;
  const int t0 = gr0 & 2047;
  const size_t bhoff = (size_t)(b * H_SZ + h) * (T_SZ * D_SZ);
  float bfl[4];
#pragma unroll
  for (int nn = 0; nn < 4; ++nn) bfl[nn] = bias[cb + nn * 16 + n];

  if (which < 2) {
    unsigned short* dst = ((which == 0) ? Qf : Kf) + bhoff;
    // Q carries 1/sqrt(D) AND log2(e): softmax exp becomes a bare v_exp_f32
    const float scl = (which == 0) ? 0.18033688f : 1.0f;
#pragma unroll
    for (int m = 0; m < 4; ++m) {
      const int tb = (t0 + m * 16) >> 4;
#pragma unroll
      for (int nn = 0; nn < 4; ++nn) {
        const int dc = nn >> 1;
        const int qd = (nn & 1) * 2 + (n >> 3);
        const int jq = n & 7;
#pragma unroll
        for (int r = 0; r < 4; ++r) {
          const int nq = quad * 4 + r;
          dst[((size_t)((tb * 2 + dc) * 4 + qd)) * 128 + nq * 8 + jq] =
              f2bf((acc[m][nn][r] + bfl[nn]) * scl);
        }
      }
    }
  } else {
    unsigned short* dst = Vf + bhoff;
    const int gb0 = t0 >> 5;
#pragma unroll
    for (int m = 0; m < 4; ++m) {
      const int gb = gb0 + (m >> 1);
#pragma unroll
      for (int nn = 0; nn < 4; ++nn) {
        // r=0..3 contiguous, 8B-aligned -> one ushort4 store
        ushort4v o;
#pragma unroll
        for (int r = 0; r < 4; ++r) o[r] = f2bf(acc[m][nn][r] + bfl[nn]);
        *(ushort4v*)(dst + ((size_t)((gb * 4 + nn) * 4 + quad)) * 128 +
                     n * 8 + (m & 1) * 4) = o;
      }
    }
  }
}

// proj: 1-D grid 512, XCD swizzle (xcd owns 8 by rows, bx inner).
__global__ __launch_bounds__(256) void proj_mfma(
    const unsigned short* __restrict__ Yf, const unsigned short* __restrict__ Wpb,
    const float* __restrict__ bias, float* __restrict__ out) {
  __shared__ unsigned short smem[16384];
  const int tid = threadIdx.x;
  const int w = tid >> 6, lane = tid & 63;
  const int quad = lane >> 4, n = lane & 15;
  const int wr = w >> 1, wc = w & 1;
  const int f = blockIdx.x;
  const int xcd = f & 7, i = f >> 3;
  const int by = xcd * 8 + (i / 8);    // [0,64)
  const int bx = i % 8;                // [0,8)
  f32x4 acc[4][4];
#pragma unroll
  for (int m = 0; m < 4; ++m)
#pragma unroll
    for (int nn = 0; nn < 4; ++nn) acc[m][nn] = (f32x4){0.f, 0.f, 0.f, 0.f};

  gemm128_mainloop(Yf, Wpb, by * 8, bx * 8, smem, acc);

  const int cb = bx * 128 + wc * 64;
  const int gr0 = by * 128 + wr * 64;
  float bfl[4];
#pragma unroll
  for (int nn = 0; nn < 4; ++nn) bfl[nn] = bias[cb + nn * 16 + n];
#pragma unroll
  for (int m = 0; m < 4; ++m)
#pragma unroll
    for (int nn = 0; nn < 4; ++nn)
#pragma unroll
      for (int r = 0; r < 4; ++r)
        out[(size_t)(gr0 + m * 16 + quad * 4 + r) * C_SZ + cb + nn * 16 + n] =
            acc[m][nn][r] + bfl[nn];
}

// ---------------------------------------------------------------------------
// attn_mfma v11: balanced pairs of 32-row chunks, 2048 waves (2/SIMD).
//  - p = 0..31, wave does chunk (63-p) then chunk p: units = 33.5 const.
//  - chunk c: nfull = c>>1 full 64-key tiles, then special tile with
//    threshold d = 2*(c&1)+mm (v8 logic, verified round 3).
//  - v7-style same-register K/V prefetch at last m-iter (mm==1); SIMD-mate
//    wave hides residual latency.
// ---------------------------------------------------------------------------
__global__ __launch_bounds__(64) void attn_mfma(
    const unsigned short* __restrict__ Qf,
    const unsigned short* __restrict__ Kf,
    const unsigned short* __restrict__ Vf, unsigned short* __restrict__ Yf) {
  const int lane = threadIdx.x;
  const int quad = lane >> 4;
  const int n = lane & 15;
  const int bx = blockIdx.x;
  const int p = bx >> 6;        // pair id 0..31
  const int bh = bx & 63;
  const int b = bh >> 4, h = bh & 15;
  const size_t bhoff = (size_t)bh * (T_SZ * D_SZ);
  const bf16x8* Qp = (const bf16x8*)(Qf + bhoff);
  const bf16x8* Kp = (const bf16x8*)(Kf + bhoff);
  const bf16x8* Vp = (const bf16x8*)(Vf + bhoff);

  auto process32 = [&](int c) {
    const int wq0 = c * 32;
    bf16x8 qfr[2][2];
#pragma unroll
    for (int mm = 0; mm < 2; ++mm) {
      const int tq = 2 * c + mm;
#pragma unroll
      for (int dc = 0; dc < 2; ++dc)
        qfr[mm][dc] = Qp[((tq * 2 + dc) * 4 + quad) * 16 + n];
    }

    bf16x8 kfr[4][2], vfr[2][4];
    f32x4 O[2][4];
    f32x4 ls[2];
#pragma unroll
    for (int mm = 0; mm < 2; ++mm) {
      ls[mm] = (f32x4){0.f, 0.f, 0.f, 0.f};
#pragma unroll
      for (int dv = 0; dv < 4; ++dv) O[mm][dv] = (f32x4){0.f, 0.f, 0.f, 0.f};
    }

    // preload K and V for tile 0 (masked later if it is the special tile)
#pragma unroll
    for (int s = 0; s < 4; ++s) {
      kfr[s][0] = Kp[((s * 2 + 0) * 4 + quad) * 16 + n];
      kfr[s][1] = Kp[((s * 2 + 1) * 4 + quad) * 16 + n];
    }
#pragma unroll
    for (int g = 0; g < 2; ++g)
#pragma unroll
      for (int dv = 0; dv < 4; ++dv)
        vfr[g][dv] = Vp[((g * 4 + dv) * 4 + quad) * 16 + n];

    const int nfull = c >> 1;

    // ---- full (unmasked) 64-key tiles ----
    for (int kt = 0; kt < nfull; ++kt) {
#pragma unroll
      for (int mm = 0; mm < 2; ++mm) {
        f32x4 st[4];
#pragma unroll
        for (int s = 0; s < 4; ++s) {
          f32x4 z = {0.f, 0.f, 0.f, 0.f};
          z = __builtin_amdgcn_mfma_f32_16x16x32_bf16(kfr[s][0], qfr[mm][0], z, 0, 0, 0);
          z = __builtin_amdgcn_mfma_f32_16x16x32_bf16(kfr[s][1], qfr[mm][1], z, 0, 0, 0);
          st[s] = z;
        }
        if (mm == 1) {
          // kfr dead for this tile: prefetch K for tile kt+1 (maybe special)
          const int tb0 = (kt + 1) * 4;
#pragma unroll
          for (int s = 0; s < 4; ++s) {
            kfr[s][0] = Kp[(((tb0 + s) * 2 + 0) * 4 + quad) * 16 + n];
            kfr[s][1] = Kp[(((tb0 + s) * 2 + 1) * 4 + quad) * 16 + n];
          }
        }
        uint4v pw[2];
#pragma unroll
        for (int s = 0; s < 4; ++s) {
          float pr[4];
#pragma unroll
          for (int r = 0; r < 4; ++r) {
            pr[r] = __builtin_amdgcn_exp2f(st[s][r]);
            ls[mm][r] += pr[r];
          }
          pw[s >> 1][(s & 1) * 2 + 0] = packbf2(pr[0], pr[1]);
          pw[s >> 1][(s & 1) * 2 + 1] = packbf2(pr[2], pr[3]);
        }
#pragma unroll
        for (int g = 0; g < 2; ++g) {
          const bf16x8 pg = __builtin_bit_cast(bf16x8, pw[g]);
#pragma unroll
          for (int dv = 0; dv < 4; ++dv)
            O[mm][dv] = __builtin_amdgcn_mfma_f32_16x16x32_bf16(
                pg, vfr[g][dv], O[mm][dv], 0, 0, 0);
        }
        if (mm == 1) {
          // vfr dead after this tile's last PV: prefetch V for tile kt+1
          const int gb0 = (kt + 1) * 2;
#pragma unroll
          for (int g = 0; g < 2; ++g)
#pragma unroll
            for (int dv = 0; dv < 4; ++dv)
              vfr[g][dv] = Vp[(((gb0 + g) * 4 + dv) * 4 + quad) * 16 + n];
        }
      }
    }

    // ---- special tile (kfr/vfr resident) ----
    {
      const int dbase = 2 * (c & 1);
#pragma unroll
      for (int mm = 0; mm < 2; ++mm) {
        const int d = dbase + mm;  // 0..3
        f32x4 st[4];
#pragma unroll
        for (int s = 0; s < 4; ++s) {
          f32x4 z = {0.f, 0.f, 0.f, 0.f};
          if (s <= d) {
            z = __builtin_amdgcn_mfma_f32_16x16x32_bf16(kfr[s][0], qfr[mm][0], z, 0, 0, 0);
            z = __builtin_amdgcn_mfma_f32_16x16x32_bf16(kfr[s][1], qfr[mm][1], z, 0, 0, 0);
          }
          st[s] = z;
        }
        uint4v pw[2] = {(uint4v){0, 0, 0, 0}, (uint4v){0, 0, 0, 0}};
#pragma unroll
        for (int s = 0; s < 4; ++s) {
          if (s <= d) {
            float pr[4];
#pragma unroll
            for (int r = 0; r < 4; ++r) {
              float v = st[s][r];
              if (s == d && quad * 4 + r > n) v = -1e30f;  // key > query
              pr[r] = __builtin_amdgcn_exp2f(v);
              ls[mm][r] += pr[r];
            }
            pw[s >> 1][(s & 1) * 2 + 0] = packbf2(pr[0], pr[1]);
            pw[s >> 1][(s & 1) * 2 + 1] = packbf2(pr[2], pr[3]);
          }
        }
#pragma unroll
        for (int g = 0; g < 2; ++g) {
          if (g * 2 <= d) {
            const bf16x8 pg = __builtin_bit_cast(bf16x8, pw[g]);
#pragma unroll
            for (int dv = 0; dv < 4; ++dv)
              O[mm][dv] = __builtin_amdgcn_mfma_f32_16x16x32_bf16(
                  pg, vfr[g][dv], O[mm][dv], 0, 0, 0);
          }
        }
      }
    }

    // ---- deferred row-sum reduction + epilogue (bf16 A-frag Yf) ----
#pragma unroll
    for (int mm = 0; mm < 2; ++mm) {
      float lt = ls[mm][0] + ls[mm][1] + ls[mm][2] + ls[mm][3];
      lt += __shfl_xor(lt, 16);
      lt += __shfl_xor(lt, 32);
      const float inv = 1.0f / lt;
      float iv[4];
#pragma unroll
      for (int r = 0; r < 4; ++r) iv[r] = __shfl(inv, quad * 4 + r);
      const int tb = (b * T_SZ + wq0 + mm * 16) >> 4;
#pragma unroll
      for (int dv = 0; dv < 4; ++dv) {
        const int kc = h * 2 + (dv >> 1);
        const int qa = (dv & 1) * 2 + (n >> 3);
        const int ja = n & 7;
#pragma unroll
        for (int r = 0; r < 4; ++r) {
          const int na = quad * 4 + r;
          Yf[((size_t)((tb * NKC + kc) * 4 + qa)) * 128 + na * 8 + ja] =
              f2bf(O[mm][dv][r] * iv[r]);
        }
      }
    }
  };

  process32(63 - p);  // long member
  process32(p);       // short member: ~33.5 half-units for every wave
}

// ---------------------------------------------------------------------------
extern "C" void kernel_launch(void* const* d_in, const int* in_sizes, int n_in,
                              void* d_out, int out_size, void* d_ws,
                              size_t ws_size, hipStream_t stream) {
  const float* x = (const float*)d_in[0];
  const float* W_attn = (const float*)d_in[1];
  const float* b_attn = (const float*)d_in[2];
  const float* W_proj = (const float*)d_in[3];
  const float* b_proj = (const float*)d_in[4];
  float* out = (float*)d_out;

  const size_t perbf = (size_t)B_SZ * H_SZ * T_SZ * D_SZ;  // 8M elems
  unsigned short* Af = (unsigned short*)d_ws;              // 16 MB
  unsigned short* Wab = Af + (size_t)BT_SZ * C_SZ;         // 6 MB
  unsigned short* Wpb = Wab + (size_t)C_SZ * C3_SZ;        // 2 MB
  unsigned short* Qf = Wpb + (size_t)C_SZ * C_SZ;          // 16 MB
  unsigned short* Kf = Qf + perbf;                         // 16 MB
  unsigned short* Vf = Kf + perbf;                         // 16 MB
  unsigned short* Yf = Vf + perbf;                         // 16 MB

  pack_all<<<6144, 256, 0, stream>>>(x, W_attn, W_proj, Af, Wab, Wpb);
  qkv_mfma<<<1536, 256, 0, stream>>>(Af, Wab, b_attn, Qf, Kf, Vf);
  attn_mfma<<<dim3(32 * B_SZ * H_SZ), 64, 0, stream>>>(Qf, Kf, Vf, Yf);
  proj_mfma<<<512, 256, 0, stream>>>(Yf, Wpb, b_proj, out);
}

// Round 9
// 230.071 us; speedup vs baseline: 1.0168x; 1.0168x over previous
//
#include <hip/hip_runtime.h>
#include <hip/hip_bf16.h>
#include <cstdint>

#define B_SZ 4
#define T_SZ 2048
#define C_SZ 1024
#define H_SZ 16
#define D_SZ 64
#define BT_SZ (B_SZ * T_SZ)     // 8192
#define C3_SZ (3 * C_SZ)        // 3072
#define NKC (C_SZ / 32)         // 32 K-chunks

typedef __attribute__((ext_vector_type(8))) short bf16x8;
typedef __attribute__((ext_vector_type(4))) float f32x4;
typedef __attribute__((ext_vector_type(4))) unsigned short ushort4v;
typedef __attribute__((ext_vector_type(4))) unsigned int uint4v;

typedef __attribute__((address_space(3))) unsigned int lds_u32;
typedef __attribute__((address_space(1))) const unsigned int glb_u32;

__device__ __forceinline__ unsigned short f2bf(float f) {
  unsigned u = __builtin_bit_cast(unsigned, f);
  u += 0x7fffu + ((u >> 16) & 1u);  // round-to-nearest-even
  return (unsigned short)(u >> 16);
}

// pack two fp32 -> two bf16 (truncating) in ONE v_perm_b32
__device__ __forceinline__ unsigned packbf2(float lo, float hi) {
  return __builtin_amdgcn_perm(__builtin_bit_cast(unsigned, hi),
                               __builtin_bit_cast(unsigned, lo), 0x07060302u);
}

// async global->LDS, 16B per lane; LDS dest = wave-uniform base + lane*16
__device__ __forceinline__ void gll16(const unsigned short* g,
                                      unsigned short* l) {
  __builtin_amdgcn_global_load_lds((glb_u32*)g, (lds_u32*)l, 16, 0, 0);
}

// ===========================================================================
// Fragment layouts (verified rounds 2-7):
//  A-frag blocked: elem(r,k) -> ((tb*NKC+kc)*4+quad)*128 + (r&15)*8 + (k&7)
//  B-frag blocked: same with n = c&15
//  Vf key-permuted PV B-operand: elem(t,d) -> ((gb*4+dv)*4+quad)*128
//      + (d&15)*8 + j,  kk=t&31, quad=(kk>>2)&3, j=(kk>>4)*4+(kk&3)
//
// Round-8:  NEVER cap with __launch_bounds__ min-waves (acc spills, 6x).
// Round-9/10: 8-phase counted-vmcnt schedules lose at this shape; the
//   2-barrier 128^2 loop at ~3 blocks/CU wins here.
// Round-13: attn v7 counters: 56.4us, VGPR 168, MfmaUtil 25%, VALU 51%,
//   Occ 10% -> latency-bound.
// Rounds 14-16 attn matrix: v7 64row/2048w=56.4 | v8 32row/4096w~63 |
//   v10 64row-paired/1024w=57 | v11 32row-paired/2048w~68. Balance alone
//   and wave-count alone do NOT convert; 32-row variants double K/V
//   traffic with the SAME serial chain -> always lose. Untried axis:
//   shorten the chain itself. => v12: split each 64-row q-tile's k-range
//   across 2 waves of a 128-thr block (disjoint ranges, same traffic,
//   chain halves); exact partial combine (no max-tracking -> O and ls
//   partials just add) via 20KB LDS.
// ===========================================================================

// ---------------------------------------------------------------------------
// pack_all: fused pack_x + pack_w(W_attn) + pack_w(W_proj)
// ---------------------------------------------------------------------------
__device__ __forceinline__ void pack_x_task(const float* __restrict__ x,
                                            unsigned short* __restrict__ Af,
                                            int task, int lane) {
  const int quad = lane >> 4, n = lane & 15;
  const int tb = task >> 5, kc = task & 31;
  const float* src = x + (size_t)(tb * 16 + n) * C_SZ + kc * 32 + quad * 8;
  float4 a = *(const float4*)src;
  float4 b = *(const float4*)(src + 4);
  ushort4v o0, o1;
  o0[0] = f2bf(a.x); o0[1] = f2bf(a.y); o0[2] = f2bf(a.z); o0[3] = f2bf(a.w);
  o1[0] = f2bf(b.x); o1[1] = f2bf(b.y); o1[2] = f2bf(b.z); o1[3] = f2bf(b.w);
  unsigned short* dst = Af + ((size_t)((tb * NKC + kc) * 4 + quad) * 16 + n) * 8;
  *(ushort4v*)dst = o0;
  *(ushort4v*)(dst + 4) = o1;
}

__device__ __forceinline__ void pack_w_task(const float* __restrict__ W,
                                            unsigned short* __restrict__ Wb,
                                            int N, int task, int lane) {
  const int quad = lane >> 4, n = lane & 15;
  const int nt = task >> 5, kc = task & 31;
  const int col = nt * 16 + n;
  const int k0 = kc * 32 + quad * 8;
  ushort4v o0, o1;
#pragma unroll
  for (int i = 0; i < 4; ++i) o0[i] = f2bf(W[(size_t)(k0 + i) * N + col]);
#pragma unroll
  for (int i = 0; i < 4; ++i) o1[i] = f2bf(W[(size_t)(k0 + 4 + i) * N + col]);
  unsigned short* dst = Wb + ((size_t)((nt * NKC + kc) * 4 + quad) * 16 + n) * 8;
  *(ushort4v*)dst = o0;
  *(ushort4v*)(dst + 4) = o1;
}

__global__ __launch_bounds__(256) void pack_all(
    const float* __restrict__ x, const float* __restrict__ Wa,
    const float* __restrict__ Wp, unsigned short* __restrict__ Af,
    unsigned short* __restrict__ Wab, unsigned short* __restrict__ Wpb) {
  const int bx = blockIdx.x;
  const int sub = threadIdx.x >> 6;
  const int lane = threadIdx.x & 63;
  if (bx < 4096) {
    pack_x_task(x, Af, bx * 4 + sub, lane);              // 512 tb x 32 kc
  } else if (bx < 4096 + 1536) {
    pack_w_task(Wa, Wab, C3_SZ, (bx - 4096) * 4 + sub, lane);  // 192 nt x 32
  } else {
    pack_w_task(Wp, Wpb, C_SZ, (bx - 5632) * 4 + sub, lane);   // 64 nt x 32
  }
}

// ---------------------------------------------------------------------------
// m97-style staged GEMM mainloop (verified round 6): 128x128 tile, BK=64,
// global_load_lds(16B) into an LDS image of the fragment-blocked layout.
// ---------------------------------------------------------------------------
__device__ __forceinline__ void gemm128_mainloop(
    const unsigned short* __restrict__ A, const unsigned short* __restrict__ B,
    int tbB, int ntB, unsigned short* smem, f32x4 acc[4][4]) {
  const int tid = threadIdx.x;
  const int w = tid >> 6, lane = tid & 63;
  const int quad = lane >> 4, n = lane & 15;
  const int wr = w >> 1, wc = w & 1;
  unsigned short* smemA = smem;         // 8192 shorts
  unsigned short* smemB = smem + 8192;  // 8192 shorts

  for (int kc0 = 0; kc0 < NKC; kc0 += 2) {
#pragma unroll
    for (int i2 = 0; i2 < 2; ++i2) {
      const int i = 2 * w + i2;
      const unsigned short* gA =
          A + ((size_t)(tbB + i) * NKC + kc0) * 512 + lane * 8;
      const unsigned short* gB =
          B + ((size_t)(ntB + i) * NKC + kc0) * 512 + lane * 8;
      gll16(gA, smemA + i * 1024);
      gll16(gA + 512, smemA + i * 1024 + 512);
      gll16(gB, smemB + i * 1024);
      gll16(gB + 512, smemB + i * 1024 + 512);
    }
    __syncthreads();
#pragma unroll
    for (int kcl = 0; kcl < 2; ++kcl) {
      bf16x8 af[4], bfr[4];
#pragma unroll
      for (int m = 0; m < 4; ++m)
        af[m] = *(const bf16x8*)(smemA + (wr * 4 + m) * 1024 +
                                 (kcl * 4 + quad) * 128 + n * 8);
#pragma unroll
      for (int nn = 0; nn < 4; ++nn)
        bfr[nn] = *(const bf16x8*)(smemB + (wc * 4 + nn) * 1024 +
                                   (kcl * 4 + quad) * 128 + n * 8);
#pragma unroll
      for (int m = 0; m < 4; ++m)
#pragma unroll
        for (int nn = 0; nn < 4; ++nn)
          acc[m][nn] = __builtin_amdgcn_mfma_f32_16x16x32_bf16(
              af[m], bfr[nn], acc[m][nn], 0, 0, 0);
    }
    __syncthreads();
  }
}

// qkv: 1-D grid 1536, XCD-aware swizzle — each XCD (f&7) owns 8 consecutive
// by rows; bx varies fastest.
__global__ __launch_bounds__(256) void qkv_mfma(
    const unsigned short* __restrict__ Af, const unsigned short* __restrict__ Wab,
    const float* __restrict__ bias, unsigned short* __restrict__ Qf,
    unsigned short* __restrict__ Kf, unsigned short* __restrict__ Vf) {
  __shared__ unsigned short smem[16384];
  const int tid = threadIdx.x;
  const int w = tid >> 6, lane = tid & 63;
  const int quad = lane >> 4, n = lane & 15;
  const int wr = w >> 1, wc = w & 1;
  const int f = blockIdx.x;
  const int xcd = f & 7, i = f >> 3;
  const int by = xcd * 8 + (i / 24);   // [0,64)
  const int bx = i % 24;               // [0,24)
  f32x4 acc[4][4];
#pragma unroll
  for (int m = 0; m < 4; ++m)
#pragma unroll
    for (int nn = 0; nn < 4; ++nn) acc[m][nn] = (f32x4){0.f, 0.f, 0.f, 0.f};

  gemm128_mainloop(Af, Wab, by * 8, bx * 8, smem, acc);

  const int cb = bx * 128 + wc * 64;
  const int which = cb >> 10;
  const int h = (cb & 1023) >> 6;
  const int gr0 = by * 128 + wr * 64;
  const int b = gr0 >> 11;
  const int t0 = gr0 & 2047;
  const size_t bhoff = (size_t)(b * H_SZ + h) * (T_SZ * D_SZ);
  float bfl[4];
#pragma unroll
  for (int nn = 0; nn < 4; ++nn) bfl[nn] = bias[cb + nn * 16 + n];

  if (which < 2) {
    unsigned short* dst = ((which == 0) ? Qf : Kf) + bhoff;
    // Q carries 1/sqrt(D) AND log2(e): softmax exp becomes a bare v_exp_f32
    const float scl = (which == 0) ? 0.18033688f : 1.0f;
#pragma unroll
    for (int m = 0; m < 4; ++m) {
      const int tb = (t0 + m * 16) >> 4;
#pragma unroll
      for (int nn = 0; nn < 4; ++nn) {
        const int dc = nn >> 1;
        const int qd = (nn & 1) * 2 + (n >> 3);
        const int jq = n & 7;
#pragma unroll
        for (int r = 0; r < 4; ++r) {
          const int nq = quad * 4 + r;
          dst[((size_t)((tb * 2 + dc) * 4 + qd)) * 128 + nq * 8 + jq] =
              f2bf((acc[m][nn][r] + bfl[nn]) * scl);
        }
      }
    }
  } else {
    unsigned short* dst = Vf + bhoff;
    const int gb0 = t0 >> 5;
#pragma unroll
    for (int m = 0; m < 4; ++m) {
      const int gb = gb0 + (m >> 1);
#pragma unroll
      for (int nn = 0; nn < 4; ++nn) {
        // r=0..3 contiguous, 8B-aligned -> one ushort4 store
        ushort4v o;
#pragma unroll
        for (int r = 0; r < 4; ++r) o[r] = f2bf(acc[m][nn][r] + bfl[nn]);
        *(ushort4v*)(dst + ((size_t)((gb * 4 + nn) * 4 + quad)) * 128 +
                     n * 8 + (m & 1) * 4) = o;
      }
    }
  }
}

// proj: 1-D grid 512, XCD swizzle (xcd owns 8 by rows, bx inner).
__global__ __launch_bounds__(256) void proj_mfma(
    const unsigned short* __restrict__ Yf, const unsigned short* __restrict__ Wpb,
    const float* __restrict__ bias, float* __restrict__ out) {
  __shared__ unsigned short smem[16384];
  const int tid = threadIdx.x;
  const int w = tid >> 6, lane = tid & 63;
  const int quad = lane >> 4, n = lane & 15;
  const int wr = w >> 1, wc = w & 1;
  const int f = blockIdx.x;
  const int xcd = f & 7, i = f >> 3;
  const int by = xcd * 8 + (i / 8);    // [0,64)
  const int bx = i % 8;                // [0,8)
  f32x4 acc[4][4];
#pragma unroll
  for (int m = 0; m < 4; ++m)
#pragma unroll
    for (int nn = 0; nn < 4; ++nn) acc[m][nn] = (f32x4){0.f, 0.f, 0.f, 0.f};

  gemm128_mainloop(Yf, Wpb, by * 8, bx * 8, smem, acc);

  const int cb = bx * 128 + wc * 64;
  const int gr0 = by * 128 + wr * 64;
  float bfl[4];
#pragma unroll
  for (int nn = 0; nn < 4; ++nn) bfl[nn] = bias[cb + nn * 16 + n];
#pragma unroll
  for (int m = 0; m < 4; ++m)
#pragma unroll
    for (int nn = 0; nn < 4; ++nn)
#pragma unroll
      for (int r = 0; r < 4; ++r)
        out[(size_t)(gr0 + m * 16 + quad * 4 + r) * C_SZ + cb + nn * 16 + n] =
            acc[m][nn][r] + bfl[nn];
}

// ---------------------------------------------------------------------------
// attn_mfma v12: 128-thread blocks; the two waves split the k-range of ONE
// 64-row q-tile (disjoint -> same K/V traffic as v7, serial chain halves).
// wave0: full tiles [0,nA); wave1: [nA,qt) + diagonal; nA=(qt+1)/2.
// No max-tracking -> partials add exactly: O=O0+O1, ls=ls0+ls1 via LDS.
// ---------------------------------------------------------------------------
__global__ __launch_bounds__(128) void attn_mfma(
    const unsigned short* __restrict__ Qf,
    const unsigned short* __restrict__ Kf,
    const unsigned short* __restrict__ Vf, unsigned short* __restrict__ Yf) {
  __shared__ f32x4 sO[64][16];   // 16 KB: wave1's O partials
  __shared__ f32x4 sLs[64][4];   //  4 KB: wave1's ls partials
  const int tid = threadIdx.x;
  const int wv = tid >> 6;       // 0 or 1
  const int lane = tid & 63;
  const int quad = lane >> 4;
  const int n = lane & 15;
  const int bx = blockIdx.x;
  const int qt = 31 - (bx >> 6);  // long blocks dispatch first
  const int bh = bx & 63;
  const int b = bh >> 4, h = bh & 15;
  const int wq0 = qt * 64;
  const size_t bhoff = (size_t)bh * (T_SZ * D_SZ);
  const bf16x8* Qp = (const bf16x8*)(Qf + bhoff);
  const bf16x8* Kp = (const bf16x8*)(Kf + bhoff);
  const bf16x8* Vp = (const bf16x8*)(Vf + bhoff);

  const int nA = (qt + 1) >> 1;
  const int kbeg = wv ? nA : 0;
  const int kend = wv ? qt : nA;      // full tiles in [kbeg, kend)
  const bool active = (wv == 1) || (nA > 0);

  bf16x8 qfr[4][2];
#pragma unroll
  for (int m = 0; m < 4; ++m) {
    const int tb = (wq0 >> 4) + m;
#pragma unroll
    for (int dc = 0; dc < 2; ++dc)
      qfr[m][dc] = Qp[((tb * 2 + dc) * 4 + quad) * 16 + n];
  }

  bf16x8 kfr[4][2], vfr[2][4];
  f32x4 O[4][4];
  f32x4 ls[4];
#pragma unroll
  for (int m = 0; m < 4; ++m) {
    ls[m] = (f32x4){0.f, 0.f, 0.f, 0.f};
#pragma unroll
    for (int dv = 0; dv < 4; ++dv) O[m][dv] = (f32x4){0.f, 0.f, 0.f, 0.f};
  }

  if (active) {
    // preload K and V for tile kbeg
#pragma unroll
    for (int s = 0; s < 4; ++s) {
      kfr[s][0] = Kp[(((kbeg * 4 + s) * 2 + 0) * 4 + quad) * 16 + n];
      kfr[s][1] = Kp[(((kbeg * 4 + s) * 2 + 1) * 4 + quad) * 16 + n];
    }
#pragma unroll
    for (int g = 0; g < 2; ++g)
#pragma unroll
      for (int dv = 0; dv < 4; ++dv)
        vfr[g][dv] = Vp[(((kbeg * 2 + g) * 4 + dv) * 4 + quad) * 16 + n];

    // ---- full (unmasked) k-tiles in [kbeg, kend) ----
    for (int kt = kbeg; kt < kend; ++kt) {
#pragma unroll
      for (int m = 0; m < 4; ++m) {
        f32x4 st[4];
#pragma unroll
        for (int s = 0; s < 4; ++s) {
          f32x4 z = {0.f, 0.f, 0.f, 0.f};
          z = __builtin_amdgcn_mfma_f32_16x16x32_bf16(kfr[s][0], qfr[m][0], z, 0, 0, 0);
          z = __builtin_amdgcn_mfma_f32_16x16x32_bf16(kfr[s][1], qfr[m][1], z, 0, 0, 0);
          st[s] = z;
        }
        if (m == 3) {
          // kfr dead for this tile: prefetch K for tile kt+1 (<= qt, valid;
          // for wave0's last iter the prefetch is harmless dead data)
          const int tb0 = (kt + 1) * 4;
#pragma unroll
          for (int s = 0; s < 4; ++s) {
            kfr[s][0] = Kp[(((tb0 + s) * 2 + 0) * 4 + quad) * 16 + n];
            kfr[s][1] = Kp[(((tb0 + s) * 2 + 1) * 4 + quad) * 16 + n];
          }
        }
        uint4v pw[2];
#pragma unroll
        for (int s = 0; s < 4; ++s) {
          float pr[4];
#pragma unroll
          for (int r = 0; r < 4; ++r) {
            pr[r] = __builtin_amdgcn_exp2f(st[s][r]);
            ls[m][r] += pr[r];
          }
          pw[s >> 1][(s & 1) * 2 + 0] = packbf2(pr[0], pr[1]);
          pw[s >> 1][(s & 1) * 2 + 1] = packbf2(pr[2], pr[3]);
        }
#pragma unroll
        for (int g = 0; g < 2; ++g) {
          const bf16x8 pg = __builtin_bit_cast(bf16x8, pw[g]);
#pragma unroll
          for (int dv = 0; dv < 4; ++dv)
            O[m][dv] = __builtin_amdgcn_mfma_f32_16x16x32_bf16(
                pg, vfr[g][dv], O[m][dv], 0, 0, 0);
        }
        if (m == 3) {
          // vfr dead: prefetch V for tile kt+1
          const int gb0 = (kt + 1) * 2;
#pragma unroll
          for (int g = 0; g < 2; ++g)
#pragma unroll
            for (int dv = 0; dv < 4; ++dv)
              vfr[g][dv] = Vp[(((gb0 + g) * 4 + dv) * 4 + quad) * 16 + n];
        }
      }
    }
  }

  // ---- diagonal k-tile (kt == qt), wave1 only; kfr/vfr resident ----
  if (wv == 1) {
#pragma unroll
    for (int m = 0; m < 4; ++m) {
      f32x4 st[4];
#pragma unroll
      for (int s = 0; s < 4; ++s) {
        f32x4 z = {0.f, 0.f, 0.f, 0.f};
        if (s <= m) {
          z = __builtin_amdgcn_mfma_f32_16x16x32_bf16(kfr[s][0], qfr[m][0], z, 0, 0, 0);
          z = __builtin_amdgcn_mfma_f32_16x16x32_bf16(kfr[s][1], qfr[m][1], z, 0, 0, 0);
        }
        st[s] = z;
      }
      uint4v pw[2] = {(uint4v){0, 0, 0, 0}, (uint4v){0, 0, 0, 0}};
#pragma unroll
      for (int s = 0; s < 4; ++s) {
        if (s <= m) {
          float pr[4];
#pragma unroll
          for (int r = 0; r < 4; ++r) {
            float v = st[s][r];
            if (s == m && quad * 4 + r > n) v = -1e30f;  // key > query
            pr[r] = __builtin_amdgcn_exp2f(v);
            ls[m][r] += pr[r];
          }
          pw[s >> 1][(s & 1) * 2 + 0] = packbf2(pr[0], pr[1]);
          pw[s >> 1][(s & 1) * 2 + 1] = packbf2(pr[2], pr[3]);
        }
      }
#pragma unroll
      for (int g = 0; g < 2; ++g) {
        if (g * 2 <= m) {
          const bf16x8 pg = __builtin_bit_cast(bf16x8, pw[g]);
#pragma unroll
          for (int dv = 0; dv < 4; ++dv)
            O[m][dv] = __builtin_amdgcn_mfma_f32_16x16x32_bf16(
                pg, vfr[g][dv], O[m][dv], 0, 0, 0);
        }
      }
    }
    // publish wave1 partials
#pragma unroll
    for (int m = 0; m < 4; ++m) {
      sLs[lane][m] = ls[m];
#pragma unroll
      for (int dv = 0; dv < 4; ++dv) sO[lane][m * 4 + dv] = O[m][dv];
    }
  }
  __syncthreads();

  if (wv == 0) {
    // combine partials, then v7 epilogue
#pragma unroll
    for (int m = 0; m < 4; ++m) {
      ls[m] += sLs[lane][m];
#pragma unroll
      for (int dv = 0; dv < 4; ++dv) O[m][dv] += sO[lane][m * 4 + dv];
    }
#pragma unroll
    for (int m = 0; m < 4; ++m) {
      float lt = ls[m][0] + ls[m][1] + ls[m][2] + ls[m][3];
      lt += __shfl_xor(lt, 16);
      lt += __shfl_xor(lt, 32);
      const float inv = 1.0f / lt;
      float iv[4];
#pragma unroll
      for (int r = 0; r < 4; ++r) iv[r] = __shfl(inv, quad * 4 + r);
      const int tb = (b * T_SZ + wq0 + m * 16) >> 4;
#pragma unroll
      for (int dv = 0; dv < 4; ++dv) {
        const int kc = h * 2 + (dv >> 1);
        const int qa = (dv & 1) * 2 + (n >> 3);
        const int ja = n & 7;
#pragma unroll
        for (int r = 0; r < 4; ++r) {
          const int na = quad * 4 + r;
          Yf[((size_t)((tb * NKC + kc) * 4 + qa)) * 128 + na * 8 + ja] =
              f2bf(O[m][dv][r] * iv[r]);
        }
      }
    }
  }
}

// ---------------------------------------------------------------------------
extern "C" void kernel_launch(void* const* d_in, const int* in_sizes, int n_in,
                              void* d_out, int out_size, void* d_ws,
                              size_t ws_size, hipStream_t stream) {
  const float* x = (const float*)d_in[0];
  const float* W_attn = (const float*)d_in[1];
  const float* b_attn = (const float*)d_in[2];
  const float* W_proj = (const float*)d_in[3];
  const float* b_proj = (const float*)d_in[4];
  float* out = (float*)d_out;

  const size_t perbf = (size_t)B_SZ * H_SZ * T_SZ * D_SZ;  // 8M elems
  unsigned short* Af = (unsigned short*)d_ws;              // 16 MB
  unsigned short* Wab = Af + (size_t)BT_SZ * C_SZ;         // 6 MB
  unsigned short* Wpb = Wab + (size_t)C_SZ * C3_SZ;        // 2 MB
  unsigned short* Qf = Wpb + (size_t)C_SZ * C_SZ;          // 16 MB
  unsigned short* Kf = Qf + perbf;                         // 16 MB
  unsigned short* Vf = Kf + perbf;                         // 16 MB
  unsigned short* Yf = Vf + perbf;                         // 16 MB

  pack_all<<<6144, 256, 0, stream>>>(x, W_attn, W_proj, Af, Wab, Wpb);
  qkv_mfma<<<1536, 256, 0, stream>>>(Af, Wab, b_attn, Qf, Kf, Vf);
  attn_mfma<<<dim3(32 * B_SZ * H_SZ), 128, 0, stream>>>(Qf, Kf, Vf, Yf);
  proj_mfma<<<512, 256, 0, stream>>>(Yf, Wpb, b_proj, out);
}

// Round 10
// 225.685 us; speedup vs baseline: 1.0366x; 1.0194x over previous
//
#include <hip/hip_runtime.h>
#include <hip/hip_bf16.h>
#include <cstdint>

#define B_SZ 4
#define T_SZ 2048
#define C_SZ 1024
#define H_SZ 16
#define D_SZ 64
#define BT_SZ (B_SZ * T_SZ)     // 8192
#define C3_SZ (3 * C_SZ)        // 3072
#define NKC (C_SZ / 32)         // 32 K-chunks

typedef __attribute__((ext_vector_type(8))) short bf16x8;
typedef __attribute__((ext_vector_type(4))) float f32x4;
typedef __attribute__((ext_vector_type(4))) unsigned short ushort4v;
typedef __attribute__((ext_vector_type(4))) unsigned int uint4v;

typedef __attribute__((address_space(3))) unsigned int lds_u32;
typedef __attribute__((address_space(1))) const unsigned int glb_u32;

__device__ __forceinline__ unsigned short f2bf(float f) {
  unsigned u = __builtin_bit_cast(unsigned, f);
  u += 0x7fffu + ((u >> 16) & 1u);  // round-to-nearest-even
  return (unsigned short)(u >> 16);
}

// pack two fp32 -> two bf16 (truncating) in ONE v_perm_b32
__device__ __forceinline__ unsigned packbf2(float lo, float hi) {
  return __builtin_amdgcn_perm(__builtin_bit_cast(unsigned, hi),
                               __builtin_bit_cast(unsigned, lo), 0x07060302u);
}

// async global->LDS, 16B per lane; LDS dest = wave-uniform base + lane*16
__device__ __forceinline__ void gll16(const unsigned short* g,
                                      unsigned short* l) {
  __builtin_amdgcn_global_load_lds((glb_u32*)g, (lds_u32*)l, 16, 0, 0);
}

// ===========================================================================
// Fragment layouts (verified rounds 2-7):
//  A-frag blocked: elem(r,k) -> ((tb*NKC+kc)*4+quad)*128 + (r&15)*8 + (k&7)
//  B-frag blocked: same with n = c&15
//  Vf key-permuted PV B-operand: elem(t,d) -> ((gb*4+dv)*4+quad)*128
//      + (d&15)*8 + j,  kk=t&31, quad=(kk>>2)&3, j=(kk>>4)*4+(kk&3)
//
// Round-8:  NEVER cap with __launch_bounds__ min-waves (acc spills, 6x).
// Round-9/10: 8-phase counted-vmcnt schedules lose at this shape; the
//   2-barrier 128^2 loop at ~3 blocks/CU wins here.
// Round-13: attn v7 counters: 56.4us, VGPR 168, MfmaUtil 25%, VALU 51%,
//   Occ 10% -> latency-bound.
// Rounds 14-17 attn matrix: v7 64row/2048w=56.4 | v8 32row~63 |
//   v10 64row-paired/1024w=57 | v11 32row-paired~68 | v12 chain-split~64.
//   Balance, wave-count, and chain-length restructures ALL fail to beat
//   ~56-57us: attn is a latency plateau for this code family. Best total:
//   round-5 config = 222.5us (qkv vec-V-store 67.4 + attn v10 + proj).
// Round-18 (this): 222.5 config + s_setprio(1) around attn MFMA clusters
//   ONLY (m191: +4-7% isolated on 1-wave-block attn; zero VGPR cost;
//   v9's regression was the bundled MFMA-ones, not setprio).
// ===========================================================================

// ---------------------------------------------------------------------------
// pack_all: fused pack_x + pack_w(W_attn) + pack_w(W_proj)
// ---------------------------------------------------------------------------
__device__ __forceinline__ void pack_x_task(const float* __restrict__ x,
                                            unsigned short* __restrict__ Af,
                                            int task, int lane) {
  const int quad = lane >> 4, n = lane & 15;
  const int tb = task >> 5, kc = task & 31;
  const float* src = x + (size_t)(tb * 16 + n) * C_SZ + kc * 32 + quad * 8;
  float4 a = *(const float4*)src;
  float4 b = *(const float4*)(src + 4);
  ushort4v o0, o1;
  o0[0] = f2bf(a.x); o0[1] = f2bf(a.y); o0[2] = f2bf(a.z); o0[3] = f2bf(a.w);
  o1[0] = f2bf(b.x); o1[1] = f2bf(b.y); o1[2] = f2bf(b.z); o1[3] = f2bf(b.w);
  unsigned short* dst = Af + ((size_t)((tb * NKC + kc) * 4 + quad) * 16 + n) * 8;
  *(ushort4v*)dst = o0;
  *(ushort4v*)(dst + 4) = o1;
}

__device__ __forceinline__ void pack_w_task(const float* __restrict__ W,
                                            unsigned short* __restrict__ Wb,
                                            int N, int task, int lane) {
  const int quad = lane >> 4, n = lane & 15;
  const int nt = task >> 5, kc = task & 31;
  const int col = nt * 16 + n;
  const int k0 = kc * 32 + quad * 8;
  ushort4v o0, o1;
#pragma unroll
  for (int i = 0; i < 4; ++i) o0[i] = f2bf(W[(size_t)(k0 + i) * N + col]);
#pragma unroll
  for (int i = 0; i < 4; ++i) o1[i] = f2bf(W[(size_t)(k0 + 4 + i) * N + col]);
  unsigned short* dst = Wb + ((size_t)((nt * NKC + kc) * 4 + quad) * 16 + n) * 8;
  *(ushort4v*)dst = o0;
  *(ushort4v*)(dst + 4) = o1;
}

__global__ __launch_bounds__(256) void pack_all(
    const float* __restrict__ x, const float* __restrict__ Wa,
    const float* __restrict__ Wp, unsigned short* __restrict__ Af,
    unsigned short* __restrict__ Wab, unsigned short* __restrict__ Wpb) {
  const int bx = blockIdx.x;
  const int sub = threadIdx.x >> 6;
  const int lane = threadIdx.x & 63;
  if (bx < 4096) {
    pack_x_task(x, Af, bx * 4 + sub, lane);              // 512 tb x 32 kc
  } else if (bx < 4096 + 1536) {
    pack_w_task(Wa, Wab, C3_SZ, (bx - 4096) * 4 + sub, lane);  // 192 nt x 32
  } else {
    pack_w_task(Wp, Wpb, C_SZ, (bx - 5632) * 4 + sub, lane);   // 64 nt x 32
  }
}

// ---------------------------------------------------------------------------
// m97-style staged GEMM mainloop (verified round 6): 128x128 tile, BK=64,
// global_load_lds(16B) into an LDS image of the fragment-blocked layout.
// ---------------------------------------------------------------------------
__device__ __forceinline__ void gemm128_mainloop(
    const unsigned short* __restrict__ A, const unsigned short* __restrict__ B,
    int tbB, int ntB, unsigned short* smem, f32x4 acc[4][4]) {
  const int tid = threadIdx.x;
  const int w = tid >> 6, lane = tid & 63;
  const int quad = lane >> 4, n = lane & 15;
  const int wr = w >> 1, wc = w & 1;
  unsigned short* smemA = smem;         // 8192 shorts
  unsigned short* smemB = smem + 8192;  // 8192 shorts

  for (int kc0 = 0; kc0 < NKC; kc0 += 2) {
#pragma unroll
    for (int i2 = 0; i2 < 2; ++i2) {
      const int i = 2 * w + i2;
      const unsigned short* gA =
          A + ((size_t)(tbB + i) * NKC + kc0) * 512 + lane * 8;
      const unsigned short* gB =
          B + ((size_t)(ntB + i) * NKC + kc0) * 512 + lane * 8;
      gll16(gA, smemA + i * 1024);
      gll16(gA + 512, smemA + i * 1024 + 512);
      gll16(gB, smemB + i * 1024);
      gll16(gB + 512, smemB + i * 1024 + 512);
    }
    __syncthreads();
#pragma unroll
    for (int kcl = 0; kcl < 2; ++kcl) {
      bf16x8 af[4], bfr[4];
#pragma unroll
      for (int m = 0; m < 4; ++m)
        af[m] = *(const bf16x8*)(smemA + (wr * 4 + m) * 1024 +
                                 (kcl * 4 + quad) * 128 + n * 8);
#pragma unroll
      for (int nn = 0; nn < 4; ++nn)
        bfr[nn] = *(const bf16x8*)(smemB + (wc * 4 + nn) * 1024 +
                                   (kcl * 4 + quad) * 128 + n * 8);
#pragma unroll
      for (int m = 0; m < 4; ++m)
#pragma unroll
        for (int nn = 0; nn < 4; ++nn)
          acc[m][nn] = __builtin_amdgcn_mfma_f32_16x16x32_bf16(
              af[m], bfr[nn], acc[m][nn], 0, 0, 0);
    }
    __syncthreads();
  }
}

// qkv: 1-D grid 1536, XCD-aware swizzle — each XCD (f&7) owns 8 consecutive
// by rows; bx varies fastest.
__global__ __launch_bounds__(256) void qkv_mfma(
    const unsigned short* __restrict__ Af, const unsigned short* __restrict__ Wab,
    const float* __restrict__ bias, unsigned short* __restrict__ Qf,
    unsigned short* __restrict__ Kf, unsigned short* __restrict__ Vf) {
  __shared__ unsigned short smem[16384];
  const int tid = threadIdx.x;
  const int w = tid >> 6, lane = tid & 63;
  const int quad = lane >> 4, n = lane & 15;
  const int wr = w >> 1, wc = w & 1;
  const int f = blockIdx.x;
  const int xcd = f & 7, i = f >> 3;
  const int by = xcd * 8 + (i / 24);   // [0,64)
  const int bx = i % 24;               // [0,24)
  f32x4 acc[4][4];
#pragma unroll
  for (int m = 0; m < 4; ++m)
#pragma unroll
    for (int nn = 0; nn < 4; ++nn) acc[m][nn] = (f32x4){0.f, 0.f, 0.f, 0.f};

  gemm128_mainloop(Af, Wab, by * 8, bx * 8, smem, acc);

  const int cb = bx * 128 + wc * 64;
  const int which = cb >> 10;
  const int h = (cb & 1023) >> 6;
  const int gr0 = by * 128 + wr * 64;
  const int b = gr0 >> 11;
  const int t0 = gr0 & 2047;
  const size_t bhoff = (size_t)(b * H_SZ + h) * (T_SZ * D_SZ);
  float bfl[4];
#pragma unroll
  for (int nn = 0; nn < 4; ++nn) bfl[nn] = bias[cb + nn * 16 + n];

  if (which < 2) {
    unsigned short* dst = ((which == 0) ? Qf : Kf) + bhoff;
    // Q carries 1/sqrt(D) AND log2(e): softmax exp becomes a bare v_exp_f32
    const float scl = (which == 0) ? 0.18033688f : 1.0f;
#pragma unroll
    for (int m = 0; m < 4; ++m) {
      const int tb = (t0 + m * 16) >> 4;
#pragma unroll
      for (int nn = 0; nn < 4; ++nn) {
        const int dc = nn >> 1;
        const int qd = (nn & 1) * 2 + (n >> 3);
        const int jq = n & 7;
#pragma unroll
        for (int r = 0; r < 4; ++r) {
          const int nq = quad * 4 + r;
          dst[((size_t)((tb * 2 + dc) * 4 + qd)) * 128 + nq * 8 + jq] =
              f2bf((acc[m][nn][r] + bfl[nn]) * scl);
        }
      }
    }
  } else {
    unsigned short* dst = Vf + bhoff;
    const int gb0 = t0 >> 5;
#pragma unroll
    for (int m = 0; m < 4; ++m) {
      const int gb = gb0 + (m >> 1);
#pragma unroll
      for (int nn = 0; nn < 4; ++nn) {
        // r=0..3 contiguous, 8B-aligned -> one ushort4 store
        ushort4v o;
#pragma unroll
        for (int r = 0; r < 4; ++r) o[r] = f2bf(acc[m][nn][r] + bfl[nn]);
        *(ushort4v*)(dst + ((size_t)((gb * 4 + nn) * 4 + quad)) * 128 +
                     n * 8 + (m & 1) * 4) = o;
      }
    }
  }
}

// proj: 1-D grid 512, XCD swizzle (xcd owns 8 by rows, bx inner).
__global__ __launch_bounds__(256) void proj_mfma(
    const unsigned short* __restrict__ Yf, const unsigned short* __restrict__ Wpb,
    const float* __restrict__ bias, float* __restrict__ out) {
  __shared__ unsigned short smem[16384];
  const int tid = threadIdx.x;
  const int w = tid >> 6, lane = tid & 63;
  const int quad = lane >> 4, n = lane & 15;
  const int wr = w >> 1, wc = w & 1;
  const int f = blockIdx.x;
  const int xcd = f & 7, i = f >> 3;
  const int by = xcd * 8 + (i / 8);    // [0,64)
  const int bx = i % 8;                // [0,8)
  f32x4 acc[4][4];
#pragma unroll
  for (int m = 0; m < 4; ++m)
#pragma unroll
    for (int nn = 0; nn < 4; ++nn) acc[m][nn] = (f32x4){0.f, 0.f, 0.f, 0.f};

  gemm128_mainloop(Yf, Wpb, by * 8, bx * 8, smem, acc);

  const int cb = bx * 128 + wc * 64;
  const int gr0 = by * 128 + wr * 64;
  float bfl[4];
#pragma unroll
  for (int nn = 0; nn < 4; ++nn) bfl[nn] = bias[cb + nn * 16 + n];
#pragma unroll
  for (int m = 0; m < 4; ++m)
#pragma unroll
    for (int nn = 0; nn < 4; ++nn)
#pragma unroll
      for (int r = 0; r < 4; ++r)
        out[(size_t)(gr0 + m * 16 + quad * 4 + r) * C_SZ + cb + nn * 16 + n] =
            acc[m][nn][r] + bfl[nn];
}

// ---------------------------------------------------------------------------
// attn_mfma v13 = v10 (paired q-tiles, double-buffered K/V, 222.5us config)
// + s_setprio(1) around the QK and PV MFMA clusters only (m191: +4-7%
// isolated on 1-wave-block attn; zero register cost).
// ---------------------------------------------------------------------------
__global__ __launch_bounds__(64) void attn_mfma(
    const unsigned short* __restrict__ Qf,
    const unsigned short* __restrict__ Kf,
    const unsigned short* __restrict__ Vf, unsigned short* __restrict__ Yf) {
  const int lane = threadIdx.x;
  const int quad = lane >> 4;
  const int n = lane & 15;
  const int bx = blockIdx.x;
  const int p = bx >> 6;        // pair id 0..15
  const int bh = bx & 63;
  const int b = bh >> 4, h = bh & 15;
  const size_t bhoff = (size_t)bh * (T_SZ * D_SZ);
  const bf16x8* Qp = (const bf16x8*)(Qf + bhoff);
  const bf16x8* Kp = (const bf16x8*)(Kf + bhoff);
  const bf16x8* Vp = (const bf16x8*)(Vf + bhoff);

  auto process = [&](int qt) {
    const int wq0 = qt * 64;
    bf16x8 qfr[4][2];
#pragma unroll
    for (int m = 0; m < 4; ++m) {
      const int tb = (wq0 >> 4) + m;
#pragma unroll
      for (int dc = 0; dc < 2; ++dc)
        qfr[m][dc] = Qp[((tb * 2 + dc) * 4 + quad) * 16 + n];
    }
    f32x4 O[4][4];
    f32x4 ls[4];
#pragma unroll
    for (int m = 0; m < 4; ++m) {
      ls[m] = (f32x4){0.f, 0.f, 0.f, 0.f};
#pragma unroll
      for (int dv = 0; dv < 4; ++dv) O[m][dv] = (f32x4){0.f, 0.f, 0.f, 0.f};
    }
    bf16x8 k0[4][2], k1[4][2], v0[2][4], v1[2][4];
    // tile 0 -> buffer 0
#pragma unroll
    for (int s = 0; s < 4; ++s) {
      k0[s][0] = Kp[((s * 2 + 0) * 4 + quad) * 16 + n];
      k0[s][1] = Kp[((s * 2 + 1) * 4 + quad) * 16 + n];
    }
#pragma unroll
    for (int g = 0; g < 2; ++g)
#pragma unroll
      for (int dv = 0; dv < 4; ++dv)
        v0[g][dv] = Vp[((g * 4 + dv) * 4 + quad) * 16 + n];

    // full tile kt from (kc,vc); prefetch tile kt+1 (<= qt always) into (kn,vn)
    auto fulltile = [&](int kt, bf16x8 (&kc)[4][2], bf16x8 (&vc)[2][4],
                        bf16x8 (&kn)[4][2], bf16x8 (&vn)[2][4]) {
      const int tb0 = (kt + 1) * 4;
#pragma unroll
      for (int s = 0; s < 4; ++s) {
        kn[s][0] = Kp[(((tb0 + s) * 2 + 0) * 4 + quad) * 16 + n];
        kn[s][1] = Kp[(((tb0 + s) * 2 + 1) * 4 + quad) * 16 + n];
      }
      const int gb0 = (kt + 1) * 2;
#pragma unroll
      for (int g = 0; g < 2; ++g)
#pragma unroll
        for (int dv = 0; dv < 4; ++dv)
          vn[g][dv] = Vp[(((gb0 + g) * 4 + dv) * 4 + quad) * 16 + n];
#pragma unroll
      for (int m = 0; m < 4; ++m) {
        f32x4 st[4];
        __builtin_amdgcn_s_setprio(1);
#pragma unroll
        for (int s = 0; s < 4; ++s) {
          f32x4 z = {0.f, 0.f, 0.f, 0.f};
          z = __builtin_amdgcn_mfma_f32_16x16x32_bf16(kc[s][0], qfr[m][0], z, 0, 0, 0);
          z = __builtin_amdgcn_mfma_f32_16x16x32_bf16(kc[s][1], qfr[m][1], z, 0, 0, 0);
          st[s] = z;
        }
        __builtin_amdgcn_s_setprio(0);
        uint4v pw[2];
#pragma unroll
        for (int s = 0; s < 4; ++s) {
          float pr[4];
#pragma unroll
          for (int r = 0; r < 4; ++r) {
            pr[r] = __builtin_amdgcn_exp2f(st[s][r]);
            ls[m][r] += pr[r];
          }
          pw[s >> 1][(s & 1) * 2 + 0] = packbf2(pr[0], pr[1]);
          pw[s >> 1][(s & 1) * 2 + 1] = packbf2(pr[2], pr[3]);
        }
        __builtin_amdgcn_s_setprio(1);
#pragma unroll
        for (int g = 0; g < 2; ++g) {
          const bf16x8 pg = __builtin_bit_cast(bf16x8, pw[g]);
#pragma unroll
          for (int dv = 0; dv < 4; ++dv)
            O[m][dv] = __builtin_amdgcn_mfma_f32_16x16x32_bf16(
                pg, vc[g][dv], O[m][dv], 0, 0, 0);
        }
        __builtin_amdgcn_s_setprio(0);
      }
    };

    auto diagtile = [&](bf16x8 (&kc)[4][2], bf16x8 (&vc)[2][4]) {
#pragma unroll
      for (int m = 0; m < 4; ++m) {
        f32x4 st[4];
        __builtin_amdgcn_s_setprio(1);
#pragma unroll
        for (int s = 0; s < 4; ++s) {
          f32x4 z = {0.f, 0.f, 0.f, 0.f};
          if (s <= m) {
            z = __builtin_amdgcn_mfma_f32_16x16x32_bf16(kc[s][0], qfr[m][0], z, 0, 0, 0);
            z = __builtin_amdgcn_mfma_f32_16x16x32_bf16(kc[s][1], qfr[m][1], z, 0, 0, 0);
          }
          st[s] = z;
        }
        __builtin_amdgcn_s_setprio(0);
        uint4v pw[2] = {(uint4v){0, 0, 0, 0}, (uint4v){0, 0, 0, 0}};
#pragma unroll
        for (int s = 0; s < 4; ++s) {
          if (s <= m) {
            float pr[4];
#pragma unroll
            for (int r = 0; r < 4; ++r) {
              float v = st[s][r];
              if (s == m && quad * 4 + r > n) v = -1e30f;  // key > query
              pr[r] = __builtin_amdgcn_exp2f(v);
              ls[m][r] += pr[r];
            }
            pw[s >> 1][(s & 1) * 2 + 0] = packbf2(pr[0], pr[1]);
            pw[s >> 1][(s & 1) * 2 + 1] = packbf2(pr[2], pr[3]);
          }
        }
        __builtin_amdgcn_s_setprio(1);
#pragma unroll
        for (int g = 0; g < 2; ++g) {
          if (g * 2 <= m) {
            const bf16x8 pg = __builtin_bit_cast(bf16x8, pw[g]);
#pragma unroll
            for (int dv = 0; dv < 4; ++dv)
              O[m][dv] = __builtin_amdgcn_mfma_f32_16x16x32_bf16(
                  pg, vc[g][dv], O[m][dv], 0, 0, 0);
          }
        }
        __builtin_amdgcn_s_setprio(0);
      }
    };

    int k2 = 0;
    for (; k2 + 2 <= qt; k2 += 2) {
      fulltile(k2, k0, v0, k1, v1);
      fulltile(k2 + 1, k1, v1, k0, v0);
    }
    if (qt & 1) {
      fulltile(qt - 1, k0, v0, k1, v1);
      diagtile(k1, v1);
    } else {
      diagtile(k0, v0);
    }

    // ---- deferred row-sum reduction + epilogue (bf16 A-frag Yf) ----
#pragma unroll
    for (int m = 0; m < 4; ++m) {
      float lt = ls[m][0] + ls[m][1] + ls[m][2] + ls[m][3];
      lt += __shfl_xor(lt, 16);
      lt += __shfl_xor(lt, 32);
      const float inv = 1.0f / lt;
      float iv[4];
#pragma unroll
      for (int r = 0; r < 4; ++r) iv[r] = __shfl(inv, quad * 4 + r);
      const int tb = (b * T_SZ + wq0 + m * 16) >> 4;
#pragma unroll
      for (int dv = 0; dv < 4; ++dv) {
        const int kc = h * 2 + (dv >> 1);
        const int qa = (dv & 1) * 2 + (n >> 3);
        const int ja = n & 7;
#pragma unroll
        for (int r = 0; r < 4; ++r) {
          const int na = quad * 4 + r;
          Yf[((size_t)((tb * NKC + kc) * 4 + qa)) * 128 + na * 8 + ja] =
              f2bf(O[m][dv][r] * iv[r]);
        }
      }
    }
  };

  process(31 - p);  // long member of the pair
  process(p);       // short member: total = 33 units for every wave
}

// ---------------------------------------------------------------------------
extern "C" void kernel_launch(void* const* d_in, const int* in_sizes, int n_in,
                              void* d_out, int out_size, void* d_ws,
                              size_t ws_size, hipStream_t stream) {
  const float* x = (const float*)d_in[0];
  const float* W_attn = (const float*)d_in[1];
  const float* b_attn = (const float*)d_in[2];
  const float* W_proj = (const float*)d_in[3];
  const float* b_proj = (const float*)d_in[4];
  float* out = (float*)d_out;

  const size_t perbf = (size_t)B_SZ * H_SZ * T_SZ * D_SZ;  // 8M elems
  unsigned short* Af = (unsigned short*)d_ws;              // 16 MB
  unsigned short* Wab = Af + (size_t)BT_SZ * C_SZ;         // 6 MB
  unsigned short* Wpb = Wab + (size_t)C_SZ * C3_SZ;        // 2 MB
  unsigned short* Qf = Wpb + (size_t)C_SZ * C_SZ;          // 16 MB
  unsigned short* Kf = Qf + perbf;                         // 16 MB
  unsigned short* Vf = Kf + perbf;                         // 16 MB
  unsigned short* Yf = Vf + perbf;                         // 16 MB

  pack_all<<<6144, 256, 0, stream>>>(x, W_attn, W_proj, Af, Wab, Wpb);
  qkv_mfma<<<1536, 256, 0, stream>>>(Af, Wab, b_attn, Qf, Kf, Vf);
  attn_mfma<<<dim3(16 * B_SZ * H_SZ), 64, 0, stream>>>(Qf, Kf, Vf, Yf);
  proj_mfma<<<512, 256, 0, stream>>>(Yf, Wpb, b_proj, out);
}

// Round 11
// 221.435 us; speedup vs baseline: 1.0565x; 1.0192x over previous
//
#include <hip/hip_runtime.h>
#include <hip/hip_bf16.h>
#include <cstdint>

#define B_SZ 4
#define T_SZ 2048
#define C_SZ 1024
#define H_SZ 16
#define D_SZ 64
#define BT_SZ (B_SZ * T_SZ)     // 8192
#define C3_SZ (3 * C_SZ)        // 3072
#define NKC (C_SZ / 32)         // 32 K-chunks

typedef __attribute__((ext_vector_type(8))) short bf16x8;
typedef __attribute__((ext_vector_type(4))) float f32x4;
typedef __attribute__((ext_vector_type(4))) unsigned short ushort4v;
typedef __attribute__((ext_vector_type(4))) unsigned int uint4v;

typedef __attribute__((address_space(3))) unsigned int lds_u32;
typedef __attribute__((address_space(1))) const unsigned int glb_u32;

__device__ __forceinline__ unsigned short f2bf(float f) {
  unsigned u = __builtin_bit_cast(unsigned, f);
  u += 0x7fffu + ((u >> 16) & 1u);  // round-to-nearest-even
  return (unsigned short)(u >> 16);
}

// pack two fp32 -> two bf16 (truncating) in ONE v_perm_b32
__device__ __forceinline__ unsigned packbf2(float lo, float hi) {
  return __builtin_amdgcn_perm(__builtin_bit_cast(unsigned, hi),
                               __builtin_bit_cast(unsigned, lo), 0x07060302u);
}

// async global->LDS, 16B per lane; LDS dest = wave-uniform base + lane*16
__device__ __forceinline__ void gll16(const unsigned short* g,
                                      unsigned short* l) {
  __builtin_amdgcn_global_load_lds((glb_u32*)g, (lds_u32*)l, 16, 0, 0);
}

// ===========================================================================
// FINAL CONFIG (restored round-6 best, 222.5us measured):
//   pack_all 6144x256 | qkv 1536x256 (vec V-store) | attn v10 1024x64 |
//   proj 512x256.
//
// Session ledger (why each alternative lost):
//  - 8-phase counted-vmcnt GEMM (128x256 and faithful 256^2 m201): 72-74us
//    vs 67.4 — K=1024 is only 16 K-tiles (prologue ~25%), fractional-round
//    grids, 1 block/CU at 128KB LDS kills cross-block overlap.
//  - __launch_bounds__ min-waves on MFMA kernels: acc spills, 6x. Never.
//  - attn restructures: v7 64row/2048w=56.4 | v8 32row~63 (2x K/V traffic)
//    | v10 64row-paired/1024w=57 | v11 32row-paired~68 | v12 2-wave
//    chain-split~64 | v13 +setprio=+3us (lockstep waves: nothing to
//    arbitrate, m190-style null). attn is latency-plateaued at ~56-57us;
//    balance/wave-count/chain-length/priority all fail to convert.
//  - qkv split into 2 dispatches for profiling: +11us (full drain) — the
//    diagnostic that exposed attn's counters (VGPR 168, MfmaUtil 25%,
//    VALU 51%, Occ 10% -> latency-bound), then reverted.
// Remaining headroom is inline-asm mainloop scheduling or a fused-attn
// rewrite — both measured-negative or out of safe step size here.
// ===========================================================================

// ---------------------------------------------------------------------------
// pack_all: fused pack_x + pack_w(W_attn) + pack_w(W_proj)
// ---------------------------------------------------------------------------
__device__ __forceinline__ void pack_x_task(const float* __restrict__ x,
                                            unsigned short* __restrict__ Af,
                                            int task, int lane) {
  const int quad = lane >> 4, n = lane & 15;
  const int tb = task >> 5, kc = task & 31;
  const float* src = x + (size_t)(tb * 16 + n) * C_SZ + kc * 32 + quad * 8;
  float4 a = *(const float4*)src;
  float4 b = *(const float4*)(src + 4);
  ushort4v o0, o1;
  o0[0] = f2bf(a.x); o0[1] = f2bf(a.y); o0[2] = f2bf(a.z); o0[3] = f2bf(a.w);
  o1[0] = f2bf(b.x); o1[1] = f2bf(b.y); o1[2] = f2bf(b.z); o1[3] = f2bf(b.w);
  unsigned short* dst = Af + ((size_t)((tb * NKC + kc) * 4 + quad) * 16 + n) * 8;
  *(ushort4v*)dst = o0;
  *(ushort4v*)(dst + 4) = o1;
}

__device__ __forceinline__ void pack_w_task(const float* __restrict__ W,
                                            unsigned short* __restrict__ Wb,
                                            int N, int task, int lane) {
  const int quad = lane >> 4, n = lane & 15;
  const int nt = task >> 5, kc = task & 31;
  const int col = nt * 16 + n;
  const int k0 = kc * 32 + quad * 8;
  ushort4v o0, o1;
#pragma unroll
  for (int i = 0; i < 4; ++i) o0[i] = f2bf(W[(size_t)(k0 + i) * N + col]);
#pragma unroll
  for (int i = 0; i < 4; ++i) o1[i] = f2bf(W[(size_t)(k0 + 4 + i) * N + col]);
  unsigned short* dst = Wb + ((size_t)((nt * NKC + kc) * 4 + quad) * 16 + n) * 8;
  *(ushort4v*)dst = o0;
  *(ushort4v*)(dst + 4) = o1;
}

__global__ __launch_bounds__(256) void pack_all(
    const float* __restrict__ x, const float* __restrict__ Wa,
    const float* __restrict__ Wp, unsigned short* __restrict__ Af,
    unsigned short* __restrict__ Wab, unsigned short* __restrict__ Wpb) {
  const int bx = blockIdx.x;
  const int sub = threadIdx.x >> 6;
  const int lane = threadIdx.x & 63;
  if (bx < 4096) {
    pack_x_task(x, Af, bx * 4 + sub, lane);              // 512 tb x 32 kc
  } else if (bx < 4096 + 1536) {
    pack_w_task(Wa, Wab, C3_SZ, (bx - 4096) * 4 + sub, lane);  // 192 nt x 32
  } else {
    pack_w_task(Wp, Wpb, C_SZ, (bx - 5632) * 4 + sub, lane);   // 64 nt x 32
  }
}

// ---------------------------------------------------------------------------
// m97-style staged GEMM mainloop (verified round 6): 128x128 tile, BK=64,
// global_load_lds(16B) into an LDS image of the fragment-blocked layout.
// 32KB LDS -> ~3-4 blocks/CU co-resident; cross-block wave overlap hides
// the barrier vmcnt drains (why it beats 8-phase variants at this shape).
// ---------------------------------------------------------------------------
__device__ __forceinline__ void gemm128_mainloop(
    const unsigned short* __restrict__ A, const unsigned short* __restrict__ B,
    int tbB, int ntB, unsigned short* smem, f32x4 acc[4][4]) {
  const int tid = threadIdx.x;
  const int w = tid >> 6, lane = tid & 63;
  const int quad = lane >> 4, n = lane & 15;
  const int wr = w >> 1, wc = w & 1;
  unsigned short* smemA = smem;         // 8192 shorts
  unsigned short* smemB = smem + 8192;  // 8192 shorts

  for (int kc0 = 0; kc0 < NKC; kc0 += 2) {
#pragma unroll
    for (int i2 = 0; i2 < 2; ++i2) {
      const int i = 2 * w + i2;
      const unsigned short* gA =
          A + ((size_t)(tbB + i) * NKC + kc0) * 512 + lane * 8;
      const unsigned short* gB =
          B + ((size_t)(ntB + i) * NKC + kc0) * 512 + lane * 8;
      gll16(gA, smemA + i * 1024);
      gll16(gA + 512, smemA + i * 1024 + 512);
      gll16(gB, smemB + i * 1024);
      gll16(gB + 512, smemB + i * 1024 + 512);
    }
    __syncthreads();
#pragma unroll
    for (int kcl = 0; kcl < 2; ++kcl) {
      bf16x8 af[4], bfr[4];
#pragma unroll
      for (int m = 0; m < 4; ++m)
        af[m] = *(const bf16x8*)(smemA + (wr * 4 + m) * 1024 +
                                 (kcl * 4 + quad) * 128 + n * 8);
#pragma unroll
      for (int nn = 0; nn < 4; ++nn)
        bfr[nn] = *(const bf16x8*)(smemB + (wc * 4 + nn) * 1024 +
                                   (kcl * 4 + quad) * 128 + n * 8);
#pragma unroll
      for (int m = 0; m < 4; ++m)
#pragma unroll
        for (int nn = 0; nn < 4; ++nn)
          acc[m][nn] = __builtin_amdgcn_mfma_f32_16x16x32_bf16(
              af[m], bfr[nn], acc[m][nn], 0, 0, 0);
    }
    __syncthreads();
  }
}

// qkv: 1-D grid 1536, XCD-aware swizzle — each XCD (f&7) owns 8 consecutive
// by rows; bx varies fastest.
__global__ __launch_bounds__(256) void qkv_mfma(
    const unsigned short* __restrict__ Af, const unsigned short* __restrict__ Wab,
    const float* __restrict__ bias, unsigned short* __restrict__ Qf,
    unsigned short* __restrict__ Kf, unsigned short* __restrict__ Vf) {
  __shared__ unsigned short smem[16384];
  const int tid = threadIdx.x;
  const int w = tid >> 6, lane = tid & 63;
  const int quad = lane >> 4, n = lane & 15;
  const int wr = w >> 1, wc = w & 1;
  const int f = blockIdx.x;
  const int xcd = f & 7, i = f >> 3;
  const int by = xcd * 8 + (i / 24);   // [0,64)
  const int bx = i % 24;               // [0,24)
  f32x4 acc[4][4];
#pragma unroll
  for (int m = 0; m < 4; ++m)
#pragma unroll
    for (int nn = 0; nn < 4; ++nn) acc[m][nn] = (f32x4){0.f, 0.f, 0.f, 0.f};

  gemm128_mainloop(Af, Wab, by * 8, bx * 8, smem, acc);

  const int cb = bx * 128 + wc * 64;
  const int which = cb >> 10;
  const int h = (cb & 1023) >> 6;
  const int gr0 = by * 128 + wr * 64;
  const int b = gr0 >> 11;
  const int t0 = gr0 & 2047;
  const size_t bhoff = (size_t)(b * H_SZ + h) * (T_SZ * D_SZ);
  float bfl[4];
#pragma unroll
  for (int nn = 0; nn < 4; ++nn) bfl[nn] = bias[cb + nn * 16 + n];

  if (which < 2) {
    unsigned short* dst = ((which == 0) ? Qf : Kf) + bhoff;
    // Q carries 1/sqrt(D) AND log2(e): softmax exp becomes a bare v_exp_f32
    const float scl = (which == 0) ? 0.18033688f : 1.0f;
#pragma unroll
    for (int m = 0; m < 4; ++m) {
      const int tb = (t0 + m * 16) >> 4;
#pragma unroll
      for (int nn = 0; nn < 4; ++nn) {
        const int dc = nn >> 1;
        const int qd = (nn & 1) * 2 + (n >> 3);
        const int jq = n & 7;
#pragma unroll
        for (int r = 0; r < 4; ++r) {
          const int nq = quad * 4 + r;
          dst[((size_t)((tb * 2 + dc) * 4 + qd)) * 128 + nq * 8 + jq] =
              f2bf((acc[m][nn][r] + bfl[nn]) * scl);
        }
      }
    }
  } else {
    unsigned short* dst = Vf + bhoff;
    const int gb0 = t0 >> 5;
#pragma unroll
    for (int m = 0; m < 4; ++m) {
      const int gb = gb0 + (m >> 1);
#pragma unroll
      for (int nn = 0; nn < 4; ++nn) {
        // r=0..3 contiguous, 8B-aligned -> one ushort4 store
        ushort4v o;
#pragma unroll
        for (int r = 0; r < 4; ++r) o[r] = f2bf(acc[m][nn][r] + bfl[nn]);
        *(ushort4v*)(dst + ((size_t)((gb * 4 + nn) * 4 + quad)) * 128 +
                     n * 8 + (m & 1) * 4) = o;
      }
    }
  }
}

// proj: 1-D grid 512, XCD swizzle (xcd owns 8 by rows, bx inner).
__global__ __launch_bounds__(256) void proj_mfma(
    const unsigned short* __restrict__ Yf, const unsigned short* __restrict__ Wpb,
    const float* __restrict__ bias, float* __restrict__ out) {
  __shared__ unsigned short smem[16384];
  const int tid = threadIdx.x;
  const int w = tid >> 6, lane = tid & 63;
  const int quad = lane >> 4, n = lane & 15;
  const int wr = w >> 1, wc = w & 1;
  const int f = blockIdx.x;
  const int xcd = f & 7, i = f >> 3;
  const int by = xcd * 8 + (i / 8);    // [0,64)
  const int bx = i % 8;                // [0,8)
  f32x4 acc[4][4];
#pragma unroll
  for (int m = 0; m < 4; ++m)
#pragma unroll
    for (int nn = 0; nn < 4; ++nn) acc[m][nn] = (f32x4){0.f, 0.f, 0.f, 0.f};

  gemm128_mainloop(Yf, Wpb, by * 8, bx * 8, smem, acc);

  const int cb = bx * 128 + wc * 64;
  const int gr0 = by * 128 + wr * 64;
  float bfl[4];
#pragma unroll
  for (int nn = 0; nn < 4; ++nn) bfl[nn] = bias[cb + nn * 16 + n];
#pragma unroll
  for (int m = 0; m < 4; ++m)
#pragma unroll
    for (int nn = 0; nn < 4; ++nn)
#pragma unroll
      for (int r = 0; r < 4; ++r)
        out[(size_t)(gr0 + m * 16 + quad * 4 + r) * C_SZ + cb + nn * 16 + n] =
            acc[m][nn][r] + bfl[nn];
}

// ---------------------------------------------------------------------------
// attn_mfma v10 (round-6 best): paired q-tiles for exact balance +
// double-buffered K/V with full-tile-ahead prefetch. Grid 1024 = 16 pairs
// x 64 bh; wave does q-tile (31-p) then (p): 33 k-tile units every wave.
// No setprio (round-10 A/B: -3us, lockstep waves have nothing to arbitrate).
// ---------------------------------------------------------------------------
__global__ __launch_bounds__(64) void attn_mfma(
    const unsigned short* __restrict__ Qf,
    const unsigned short* __restrict__ Kf,
    const unsigned short* __restrict__ Vf, unsigned short* __restrict__ Yf) {
  const int lane = threadIdx.x;
  const int quad = lane >> 4;
  const int n = lane & 15;
  const int bx = blockIdx.x;
  const int p = bx >> 6;        // pair id 0..15
  const int bh = bx & 63;
  const int b = bh >> 4, h = bh & 15;
  const size_t bhoff = (size_t)bh * (T_SZ * D_SZ);
  const bf16x8* Qp = (const bf16x8*)(Qf + bhoff);
  const bf16x8* Kp = (const bf16x8*)(Kf + bhoff);
  const bf16x8* Vp = (const bf16x8*)(Vf + bhoff);

  auto process = [&](int qt) {
    const int wq0 = qt * 64;
    bf16x8 qfr[4][2];
#pragma unroll
    for (int m = 0; m < 4; ++m) {
      const int tb = (wq0 >> 4) + m;
#pragma unroll
      for (int dc = 0; dc < 2; ++dc)
        qfr[m][dc] = Qp[((tb * 2 + dc) * 4 + quad) * 16 + n];
    }
    f32x4 O[4][4];
    f32x4 ls[4];
#pragma unroll
    for (int m = 0; m < 4; ++m) {
      ls[m] = (f32x4){0.f, 0.f, 0.f, 0.f};
#pragma unroll
      for (int dv = 0; dv < 4; ++dv) O[m][dv] = (f32x4){0.f, 0.f, 0.f, 0.f};
    }
    bf16x8 k0[4][2], k1[4][2], v0[2][4], v1[2][4];
    // tile 0 -> buffer 0
#pragma unroll
    for (int s = 0; s < 4; ++s) {
      k0[s][0] = Kp[((s * 2 + 0) * 4 + quad) * 16 + n];
      k0[s][1] = Kp[((s * 2 + 1) * 4 + quad) * 16 + n];
    }
#pragma unroll
    for (int g = 0; g < 2; ++g)
#pragma unroll
      for (int dv = 0; dv < 4; ++dv)
        v0[g][dv] = Vp[((g * 4 + dv) * 4 + quad) * 16 + n];

    // full tile kt from (kc,vc); prefetch tile kt+1 (<= qt always) into (kn,vn)
    auto fulltile = [&](int kt, bf16x8 (&kc)[4][2], bf16x8 (&vc)[2][4],
                        bf16x8 (&kn)[4][2], bf16x8 (&vn)[2][4]) {
      const int tb0 = (kt + 1) * 4;
#pragma unroll
      for (int s = 0; s < 4; ++s) {
        kn[s][0] = Kp[(((tb0 + s) * 2 + 0) * 4 + quad) * 16 + n];
        kn[s][1] = Kp[(((tb0 + s) * 2 + 1) * 4 + quad) * 16 + n];
      }
      const int gb0 = (kt + 1) * 2;
#pragma unroll
      for (int g = 0; g < 2; ++g)
#pragma unroll
        for (int dv = 0; dv < 4; ++dv)
          vn[g][dv] = Vp[(((gb0 + g) * 4 + dv) * 4 + quad) * 16 + n];
#pragma unroll
      for (int m = 0; m < 4; ++m) {
        f32x4 st[4];
#pragma unroll
        for (int s = 0; s < 4; ++s) {
          f32x4 z = {0.f, 0.f, 0.f, 0.f};
          z = __builtin_amdgcn_mfma_f32_16x16x32_bf16(kc[s][0], qfr[m][0], z, 0, 0, 0);
          z = __builtin_amdgcn_mfma_f32_16x16x32_bf16(kc[s][1], qfr[m][1], z, 0, 0, 0);
          st[s] = z;
        }
        uint4v pw[2];
#pragma unroll
        for (int s = 0; s < 4; ++s) {
          float pr[4];
#pragma unroll
          for (int r = 0; r < 4; ++r) {
            pr[r] = __builtin_amdgcn_exp2f(st[s][r]);
            ls[m][r] += pr[r];
          }
          pw[s >> 1][(s & 1) * 2 + 0] = packbf2(pr[0], pr[1]);
          pw[s >> 1][(s & 1) * 2 + 1] = packbf2(pr[2], pr[3]);
        }
#pragma unroll
        for (int g = 0; g < 2; ++g) {
          const bf16x8 pg = __builtin_bit_cast(bf16x8, pw[g]);
#pragma unroll
          for (int dv = 0; dv < 4; ++dv)
            O[m][dv] = __builtin_amdgcn_mfma_f32_16x16x32_bf16(
                pg, vc[g][dv], O[m][dv], 0, 0, 0);
        }
      }
    };

    auto diagtile = [&](bf16x8 (&kc)[4][2], bf16x8 (&vc)[2][4]) {
#pragma unroll
      for (int m = 0; m < 4; ++m) {
        f32x4 st[4];
#pragma unroll
        for (int s = 0; s < 4; ++s) {
          f32x4 z = {0.f, 0.f, 0.f, 0.f};
          if (s <= m) {
            z = __builtin_amdgcn_mfma_f32_16x16x32_bf16(kc[s][0], qfr[m][0], z, 0, 0, 0);
            z = __builtin_amdgcn_mfma_f32_16x16x32_bf16(kc[s][1], qfr[m][1], z, 0, 0, 0);
          }
          st[s] = z;
        }
        uint4v pw[2] = {(uint4v){0, 0, 0, 0}, (uint4v){0, 0, 0, 0}};
#pragma unroll
        for (int s = 0; s < 4; ++s) {
          if (s <= m) {
            float pr[4];
#pragma unroll
            for (int r = 0; r < 4; ++r) {
              float v = st[s][r];
              if (s == m && quad * 4 + r > n) v = -1e30f;  // key > query
              pr[r] = __builtin_amdgcn_exp2f(v);
              ls[m][r] += pr[r];
            }
            pw[s >> 1][(s & 1) * 2 + 0] = packbf2(pr[0], pr[1]);
            pw[s >> 1][(s & 1) * 2 + 1] = packbf2(pr[2], pr[3]);
          }
        }
#pragma unroll
        for (int g = 0; g < 2; ++g) {
          if (g * 2 <= m) {
            const bf16x8 pg = __builtin_bit_cast(bf16x8, pw[g]);
#pragma unroll
            for (int dv = 0; dv < 4; ++dv)
              O[m][dv] = __builtin_amdgcn_mfma_f32_16x16x32_bf16(
                  pg, vc[g][dv], O[m][dv], 0, 0, 0);
          }
        }
      }
    };

    int k2 = 0;
    for (; k2 + 2 <= qt; k2 += 2) {
      fulltile(k2, k0, v0, k1, v1);
      fulltile(k2 + 1, k1, v1, k0, v0);
    }
    if (qt & 1) {
      fulltile(qt - 1, k0, v0, k1, v1);
      diagtile(k1, v1);
    } else {
      diagtile(k0, v0);
    }

    // ---- deferred row-sum reduction + epilogue (bf16 A-frag Yf) ----
#pragma unroll
    for (int m = 0; m < 4; ++m) {
      float lt = ls[m][0] + ls[m][1] + ls[m][2] + ls[m][3];
      lt += __shfl_xor(lt, 16);
      lt += __shfl_xor(lt, 32);
      const float inv = 1.0f / lt;
      float iv[4];
#pragma unroll
      for (int r = 0; r < 4; ++r) iv[r] = __shfl(inv, quad * 4 + r);
      const int tb = (b * T_SZ + wq0 + m * 16) >> 4;
#pragma unroll
      for (int dv = 0; dv < 4; ++dv) {
        const int kc = h * 2 + (dv >> 1);
        const int qa = (dv & 1) * 2 + (n >> 3);
        const int ja = n & 7;
#pragma unroll
        for (int r = 0; r < 4; ++r) {
          const int na = quad * 4 + r;
          Yf[((size_t)((tb * NKC + kc) * 4 + qa)) * 128 + na * 8 + ja] =
              f2bf(O[m][dv][r] * iv[r]);
        }
      }
    }
  };

  process(31 - p);  // long member of the pair
  process(p);       // short member: total = 33 units for every wave
}

// ---------------------------------------------------------------------------
extern "C" void kernel_launch(void* const* d_in, const int* in_sizes, int n_in,
                              void* d_out, int out_size, void* d_ws,
                              size_t ws_size, hipStream_t stream) {
  const float* x = (const float*)d_in[0];
  const float* W_attn = (const float*)d_in[1];
  const float* b_attn = (const float*)d_in[2];
  const float* W_proj = (const float*)d_in[3];
  const float* b_proj = (const float*)d_in[4];
  float* out = (float*)d_out;

  const size_t perbf = (size_t)B_SZ * H_SZ * T_SZ * D_SZ;  // 8M elems
  unsigned short* Af = (unsigned short*)d_ws;              // 16 MB
  unsigned short* Wab = Af + (size_t)BT_SZ * C_SZ;         // 6 MB
  unsigned short* Wpb = Wab + (size_t)C_SZ * C3_SZ;        // 2 MB
  unsigned short* Qf = Wpb + (size_t)C_SZ * C_SZ;          // 16 MB
  unsigned short* Kf = Qf + perbf;                         // 16 MB
  unsigned short* Vf = Kf + perbf;                         // 16 MB
  unsigned short* Yf = Vf + perbf;                         // 16 MB

  pack_all<<<6144, 256, 0, stream>>>(x, W_attn, W_proj, Af, Wab, Wpb);
  qkv_mfma<<<1536, 256, 0, stream>>>(Af, Wab, b_attn, Qf, Kf, Vf);
  attn_mfma<<<dim3(16 * B_SZ * H_SZ), 64, 0, stream>>>(Qf, Kf, Vf, Yf);
  proj_mfma<<<512, 256, 0, stream>>>(Yf, Wpb, b_proj, out);
}